// Round 8
// baseline (174.014 us; speedup 1.0000x reference)
//
#include <hip/hip_runtime.h>

// Problem constants (fixed by the reference's setup_inputs)
#define C_DIM 64
#define P_DIM 16
#define K_DIM 9              // K1*K1
#define ZROW 10              // padded Zb row (ushorts) per (n,p): 20 B
#define ZNODE (P_DIM * ZROW) // 160 ushorts = 320 B per node
#define NT 10                // n-tiles of 16 output columns (160 = padded layout)
#define INV2S 0.35355339059327373f  // 1/(2*sqrt(2))

typedef __attribute__((ext_vector_type(8))) short short8v;  // 8 bf16 (4 VGPRs)
typedef __attribute__((ext_vector_type(4))) float f32x4;    // MFMA accumulator
typedef uint uint4a __attribute__((ext_vector_type(4), aligned(4)));

__device__ __forceinline__ ushort f2bf(float f) {
    uint u = __builtin_bit_cast(uint, f);
    return (ushort)((u + 0x7FFFu + ((u >> 16) & 1u)) >> 16);   // RNE
}
__device__ __forceinline__ float bf2f(ushort h) {
    return __builtin_bit_cast(float, ((uint)h) << 16);
}

// LDS row stride (in ushorts) for the W' hi/lo tables: 72*2B = 144B rows,
// 16B aligned; ds_read_b128 lane bank stride 36%32=4 -> <=2-way (free).
#define WSTRIDE 72

// ---------------------------------------------------------------------------
// Kernel 1 (MFMA), r5 structure (64 rows/block — measured-best occupancy):
// (a) bias-init out, (b) pose -> packed-bf16 table (gated),
// (c) Zb[n][s] (s = p*10+k, padded) = sum_c x[n,c]*W[p,k,c], split-bf16 MFMA.
// Permuted 160-row W' LDS table: MFMA output column j IS the padded slot.
// ---------------------------------------------------------------------------
__global__ __launch_bounds__(256) void z_gemm_kernel(const float* __restrict__ x,
                                                     const float* __restrict__ W,
                                                     const float* __restrict__ bias,
                                                     const float* __restrict__ pose,
                                                     float* __restrict__ out,
                                                     ushort* __restrict__ Zb,
                                                     uint* __restrict__ pose_bf,
                                                     int N) {
    __shared__ ushort w_hi[160 * WSTRIDE];   // 23040 B
    __shared__ ushort w_lo[160 * WSTRIDE];   // 23040 B

    const int tid = threadIdx.x;
    const int block_row = blockIdx.x * 64;

    // (a) bias-init this block's slice of out: 64 rows x 16 = 256 float4s
    {
        const float4 b4 = ((const float4*)bias)[tid & 3];
        const int o4 = block_row * 4 + tid;          // float4 index into out
        if (o4 < N * 4) ((float4*)out)[o4] = b4;
    }

    // (b) pose -> packed bf16 (measured -3us on edge_kernel, r4 vs r5)
    if (pose_bf != nullptr) {
        for (int i = tid; i < 64 * P_DIM; i += 256) {
            const int r = block_row + (i >> 4);
            if (r < N) {
                const float2 ab = ((const float2*)pose)[(size_t)r * P_DIM + (i & 15)];
                pose_bf[(size_t)r * P_DIM + (i & 15)] =
                    (uint)f2bf(ab.x) | ((uint)f2bf(ab.y) << 16);
            }
        }
    }

    // (c) stage permuted W' (160x64 f32 -> bf16 hi/lo): 5120 float2 loads
    for (int i = tid; i < 160 * (C_DIM / 2); i += 256) {
        const int s  = i >> 5;           // W' row (0..159)
        const int k2 = i & 31;           // float2 index within row
        const int p  = s / 10;
        const int k  = s - p * 10;
        float2 w2 = make_float2(0.0f, 0.0f);
        if (k < 9) w2 = ((const float2*)W)[(p * 9 + k) * (C_DIM / 2) + k2];
        const int o = s * WSTRIDE + k2 * 2;
        const ushort h0 = f2bf(w2.x);
        const ushort h1 = f2bf(w2.y);
        w_hi[o]     = h0;
        w_hi[o + 1] = h1;
        w_lo[o]     = f2bf(w2.x - bf2f(h0));
        w_lo[o + 1] = f2bf(w2.y - bf2f(h1));
    }
    __syncthreads();

    const int lane = tid & 63;
    const int wv   = tid >> 6;    // wave -> m-subtile (16 rows)
    const int col  = lane & 15;   // A row within tile / B,C/D column
    const int kg   = lane >> 4;   // k-group 0..3

    // A operand: lane supplies x[arow][kg*8 + e (+32*chunk)], split hi/lo.
    const int arow = block_row + wv * 16 + col;
    const float* xr = x + (size_t)(arow < N ? arow : 0) * C_DIM;
    float4 x0 = ((const float4*)xr)[kg * 2];
    float4 x1 = ((const float4*)xr)[kg * 2 + 1];
    float4 x2 = ((const float4*)xr)[8 + kg * 2];
    float4 x3 = ((const float4*)xr)[8 + kg * 2 + 1];
    if (arow >= N) {
        x0 = x1 = x2 = x3 = make_float4(0.f, 0.f, 0.f, 0.f);
    }

    short8v a_hi0, a_lo0, a_hi1, a_lo1;
    {
        const float t0[8] = {x0.x, x0.y, x0.z, x0.w, x1.x, x1.y, x1.z, x1.w};
        const float t1[8] = {x2.x, x2.y, x2.z, x2.w, x3.x, x3.y, x3.z, x3.w};
        #pragma unroll
        for (int e = 0; e < 8; ++e) {
            const ushort h = f2bf(t0[e]);
            a_hi0[e] = (short)h;
            a_lo0[e] = (short)f2bf(t0[e] - bf2f(h));
            const ushort g = f2bf(t1[e]);
            a_hi1[e] = (short)g;
            a_lo1[e] = (short)f2bf(t1[e] - bf2f(g));
        }
    }

    // C/D layout (HW-verified): col = lane&15, row = kg*4 + reg
    const int orow0 = block_row + wv * 16 + kg * 4;

    #pragma unroll
    for (int nt = 0; nt < NT; ++nt) {
        const int j = nt * 16 + col;            // padded slot (0..159)
        const ushort* bhp = &w_hi[j * WSTRIDE + kg * 8];
        const ushort* blp = &w_lo[j * WSTRIDE + kg * 8];
        const short8v bh0 = *(const short8v*)bhp;          // c = kg*8+e
        const short8v bh1 = *(const short8v*)(bhp + 32);   // c = 32+kg*8+e
        const short8v bl0 = *(const short8v*)blp;
        const short8v bl1 = *(const short8v*)(blp + 32);

        f32x4 acc = {0.f, 0.f, 0.f, 0.f};
        // split-bf16 3-product: lo terms first, hi*hi last
        acc = __builtin_amdgcn_mfma_f32_16x16x32_bf16(a_lo0, bh0, acc, 0, 0, 0);
        acc = __builtin_amdgcn_mfma_f32_16x16x32_bf16(a_hi0, bl0, acc, 0, 0, 0);
        acc = __builtin_amdgcn_mfma_f32_16x16x32_bf16(a_lo1, bh1, acc, 0, 0, 0);
        acc = __builtin_amdgcn_mfma_f32_16x16x32_bf16(a_hi1, bl1, acc, 0, 0, 0);
        acc = __builtin_amdgcn_mfma_f32_16x16x32_bf16(a_hi0, bh0, acc, 0, 0, 0);
        acc = __builtin_amdgcn_mfma_f32_16x16x32_bf16(a_hi1, bh1, acc, 0, 0, 0);

        // direct store: slot == j; 16 col-lanes -> 32B contiguous chunks
        #pragma unroll
        for (int r = 0; r < 4; ++r) {
            const int row = orow0 + r;
            if (row < N) Zb[(size_t)row * ZNODE + j] = f2bf(acc[r]);
        }
    }
}

// ---------------------------------------------------------------------------
// Kernel 2: edge messages + scatter-add, XCD-PARTITIONED by c-range.
// block b: sub-range = b&7 (aligned to XCD under round-robin dispatch),
// chunk-group = b>>3. Each wave scans 4 chunks of 64 candidate edges
// (coalesced nontemporal c/r loads), ballots the in-range ones (~8/64),
// and processes hits 4-at-a-time (16 lanes per edge) via uniform SALU
// bit-extraction + shfl. Each XCD's L2 then only holds a 2MB Zb slice.
// Correct under ANY blockIdx->XCD mapping: every (chunk, sub) pair is
// covered exactly once and sub_of(c) is a pure deterministic function.
// ---------------------------------------------------------------------------
template <bool USEBF>
__global__ __launch_bounds__(256) void edge_kernel(const int* __restrict__ ei,
                                                   const float* __restrict__ pos,
                                                   const float* __restrict__ pose,
                                                   const uint* __restrict__ pose_bf,
                                                   const ushort* __restrict__ Zb,
                                                   float* __restrict__ out,
                                                   int E, float invn8) {
    const int wid  = threadIdx.x >> 6;
    const int lane = threadIdx.x & 63;
    const int p    = lane & 15;      // spline-tap lane within group
    const int g    = lane >> 4;      // group 0..3 (one edge per group)
    const int sub  = blockIdx.x & 7;
    const int cg0  = (blockIdx.x >> 3) * 16 + wid * 4;   // first chunk

    #pragma unroll
    for (int it = 0; it < 4; ++it) {
        const int chunk = cg0 + it;
        const int e  = chunk * 64 + lane;
        const bool ev = (e < E);
        const int ee = ev ? e : 0;
        // nontemporal: streamed once per sub-range, don't pollute L2
        const int cl = __builtin_nontemporal_load(ei + (size_t)E + ee);
        const int rl = __builtin_nontemporal_load(ei + ee);
        const int subc = (int)((float)cl * invn8);
        const bool inr = ev && (subc == sub);

        unsigned long long mask = __ballot(inr);
        while (mask) {
            // extract up to 4 hit lane-indices (uniform SALU loop)
            uint packed = 0;
            int nv = 0;
            #pragma unroll
            for (int t = 0; t < 4; ++t) {
                if (mask) {
                    const uint li = (uint)__builtin_ctzll(mask);
                    mask &= (mask - 1);
                    packed |= li << (8 * t);
                    ++nv;
                }
            }
            const uint Lg = (packed >> ((lane >> 1) & 24)) & 63u;  // g*8 shift
            const bool gv = (g < nv);
            int rg = __shfl(rl, (int)Lg, 64);
            int cg = __shfl(cl, (int)Lg, 64);
            rg = gv ? rg : 0;
            cg = gv ? cg : 0;

            // --- heavy path: 16 lanes per edge ---
            const float2 pc = ((const float2*)pos)[cg];
            const float2 pr = ((const float2*)pos)[rg];
            const float d0 = (pc.x - pr.x) * INV2S;
            const float d1 = (pc.y - pr.y) * INV2S;

            float a_, b_;
            if (USEBF) {
                const uint ab = pose_bf[(size_t)rg * P_DIM + p];
                a_ = bf2f((ushort)(ab & 0xffffu));
                b_ = bf2f((ushort)(ab >> 16));
            } else {
                const float2 ab = ((const float2*)pose)[(size_t)rg * P_DIM + p];
                a_ = ab.x;
                b_ = ab.y;
            }

            const uint* Zp = (const uint*)(Zb + (size_t)cg * ZNODE) + p * (ZROW / 2);
            const uint4a qv = *(const uint4a*)Zp;   // dwordx4
            const uint   q4 = Zp[4];

            const float p0 = fmaf(a_, d0, fmaf(-b_, d1, 0.5f));
            const float p1 = fmaf(b_, d0, fmaf( a_, d1, 0.5f));

            const float v0 = fminf(fmaxf(p0, 0.0f), 1.0f) * 2.0f;
            const float v1 = fminf(fmaxf(p1, 0.0f), 1.0f) * 2.0f;
            // window base: b0 = (v0>=1), b1 = (v1>=1); fracs relative to base.
            // (at v==2: base 1, frac 1 -> weight on column 2; matches the
            //  reference's clamped i00==i01==2 case exactly)
            const bool b0 = (v0 >= 1.0f);
            const bool b1 = (v1 >= 1.0f);
            const float f0 = v0 - (b0 ? 1.0f : 0.0f);
            const float f1 = v1 - (b1 ? 1.0f : 0.0f);

            // 6-element window w0..w5 = e(3*b1) .. e(3*b1+5) as 3 dwords
            const uint A0 = qv[0], A1 = qv[1], A2 = qv[2], A3 = qv[3], A4 = q4;
            const uint W0 = b1 ? ((A1 >> 16) | (A2 << 16)) : A0;
            const uint W1 = b1 ? ((A2 >> 16) | (A3 << 16)) : A1;
            const uint W2 = b1 ? ((A3 >> 16) | (A4 << 16)) : A2;
            // taps: z00=w(b0), z10=w(b0+1), z01=w(b0+3), z11=w(b0+4)
            const uint s = b0 ? 16u : 0u;
            const float z00 = bf2f((ushort)(W0 >> s));
            const float z10 = bf2f((ushort)(b0 ? (W1 & 0xffffu) : (W0 >> 16)));
            const float z01 = bf2f((ushort)(b0 ? (W2 & 0xffffu) : (W1 >> 16)));
            const float z11 = bf2f((ushort)(W2 >> s));

            const float w00 = (1.0f - f0) * (1.0f - f1);
            const float w01 = (1.0f - f0) * f1;
            const float w10 = f0 * (1.0f - f1);
            const float w11 = f0 * f1;

            float msg = w00 * z00;
            msg = fmaf(w01, z01, msg);
            msg = fmaf(w10, z10, msg);
            msg = fmaf(w11, z11, msg);

            if (gv) atomicAdd(&out[(size_t)rg * P_DIM + p], msg);
        }
    }
}

// ---------------------------------------------------------------------------
extern "C" void kernel_launch(void* const* d_in, const int* in_sizes, int n_in,
                              void* d_out, int out_size, void* d_ws, size_t ws_size,
                              hipStream_t stream) {
    const float* x    = (const float*)d_in[0];
    const float* pos  = (const float*)d_in[1];
    const float* pose = (const float*)d_in[2];
    const float* W    = (const float*)d_in[3];
    const float* bias = (const float*)d_in[4];
    const int*   ei   = (const int*)d_in[5];

    const int N = in_sizes[0] / C_DIM;   // 50000
    const int E = in_sizes[5] / 2;       // 800000

    float* out = (float*)d_out;
    ushort* Zb = (ushort*)d_ws;          // N*160 bf16 = 16.0 MB (padded rows)

    // pose-bf16 table only if the workspace actually has room for it
    const size_t zb_bytes   = (size_t)N * ZNODE * sizeof(ushort);
    const size_t pose_bytes = (size_t)N * P_DIM * sizeof(uint);
    uint* pose_bf = (ws_size >= zb_bytes + pose_bytes)
                        ? (uint*)((char*)d_ws + zb_bytes) : nullptr;

    z_gemm_kernel<<<(N + 63) / 64, 256, 0, stream>>>(x, W, bias, pose, out, Zb, pose_bf, N);

    // grid: 8 sub-ranges x chunk-groups (16 chunks of 64 edges per block)
    const int NC = (E + 63) / 64;
    const int cgroups = (NC + 15) / 16;
    const float invn8 = 1.0f / (float)((N + 7) / 8);
    if (pose_bf != nullptr)
        edge_kernel<true><<<cgroups * 8, 256, 0, stream>>>(ei, pos, pose, pose_bf, Zb, out, E, invn8);
    else
        edge_kernel<false><<<cgroups * 8, 256, 0, stream>>>(ei, pos, pose, pose_bf, Zb, out, E, invn8);
}

// Round 9
// 144.992 us; speedup vs baseline: 1.2002x; 1.2002x over previous
//
#include <hip/hip_runtime.h>

// Problem constants (fixed by the reference's setup_inputs)
#define C_DIM 64
#define P_DIM 16
#define K_DIM 9
#define PK (P_DIM * K_DIM)   // 144 — UNPADDED rows (r2's fastest-gemm layout)
#define NT 9
#define INV2S 0.35355339059327373f  // 1/(2*sqrt(2))

typedef __attribute__((ext_vector_type(8))) short short8v;  // 8 bf16 (4 VGPRs)
typedef __attribute__((ext_vector_type(4))) float f32x4;    // MFMA accumulator
// 16B vector, 4B alignment: clang emits global_load_dwordx4 (gfx9+ handles it)
typedef uint uint4a __attribute__((ext_vector_type(4), aligned(4)));

__device__ __forceinline__ ushort f2bf(float f) {
    uint u = __builtin_bit_cast(uint, f);
    return (ushort)((u + 0x7FFFu + ((u >> 16) & 1u)) >> 16);   // RNE
}
__device__ __forceinline__ float bf2f(ushort h) {
    return __builtin_bit_cast(float, ((uint)h) << 16);
}

// LDS row stride (in ushorts) for the W hi/lo tables: 72*2B = 144B rows,
// 16B aligned; ds_read_b128 lane bank stride 36%32=4 -> <=2-way (free).
#define WSTRIDE 72

// ---------------------------------------------------------------------------
// Kernel 1 (MFMA) — r2's measured-best structure (gemm ~26us inferred):
// (a) bias-init out, (b) pose -> packed-bf16 table (gated),
// (c) Zb[n*144 + p*9+k] = sum_c x[n,c]*W[p,k,c] via split-bf16 3-product MFMA.
// 64 rows/block, 4 waves; linear (non-permuted) W staging, NT=9, direct
// scatter stores (16 col-lanes -> 32B contiguous per (row,nt)).
// ---------------------------------------------------------------------------
__global__ __launch_bounds__(256) void z_gemm_kernel(const float* __restrict__ x,
                                                     const float* __restrict__ W,
                                                     const float* __restrict__ bias,
                                                     const float* __restrict__ pose,
                                                     float* __restrict__ out,
                                                     ushort* __restrict__ Zb,
                                                     uint* __restrict__ pose_bf,
                                                     int N) {
    __shared__ ushort w_hi[PK * WSTRIDE];   // 20736 B
    __shared__ ushort w_lo[PK * WSTRIDE];   // 20736 B

    const int tid = threadIdx.x;
    const int block_row = blockIdx.x * 64;

    // (a) bias-init this block's slice of out: 64 rows x 16 = 256 float4s
    {
        const float4 b4 = ((const float4*)bias)[tid & 3];
        const int o4 = block_row * 4 + tid;          // float4 index into out
        if (o4 < N * 4) ((float4*)out)[o4] = b4;
    }

    // (b) pose -> packed bf16 (measured -3us on edge_kernel, r4 vs r5)
    if (pose_bf != nullptr) {
        for (int i = tid; i < 64 * P_DIM; i += 256) {
            const int r = block_row + (i >> 4);
            if (r < N) {
                const float2 ab = ((const float2*)pose)[(size_t)r * P_DIM + (i & 15)];
                pose_bf[(size_t)r * P_DIM + (i & 15)] =
                    (uint)f2bf(ab.x) | ((uint)f2bf(ab.y) << 16);
            }
        }
    }

    // (c) stage W (144x64 f32 -> bf16 hi/lo), LINEAR: 4608 float2 loads
    for (int i = tid; i < PK * (C_DIM / 2); i += 256) {
        const int n  = i >> 5;           // W row (0..143)
        const int k2 = i & 31;           // float2 index within row
        const float2 w2 = ((const float2*)W)[i];
        const int o = n * WSTRIDE + k2 * 2;
        const ushort h0 = f2bf(w2.x);
        const ushort h1 = f2bf(w2.y);
        w_hi[o]     = h0;
        w_hi[o + 1] = h1;
        w_lo[o]     = f2bf(w2.x - bf2f(h0));
        w_lo[o + 1] = f2bf(w2.y - bf2f(h1));
    }
    __syncthreads();

    const int lane = tid & 63;
    const int wv   = tid >> 6;    // wave -> m-subtile (16 rows)
    const int col  = lane & 15;   // A row within tile / B,C/D column
    const int kg   = lane >> 4;   // k-group 0..3

    // A operand: lane supplies x[arow][kg*8 + e (+32*chunk)], split hi/lo.
    const int arow = block_row + wv * 16 + col;
    const float* xr = x + (size_t)(arow < N ? arow : 0) * C_DIM;
    float4 x0 = ((const float4*)xr)[kg * 2];
    float4 x1 = ((const float4*)xr)[kg * 2 + 1];
    float4 x2 = ((const float4*)xr)[8 + kg * 2];
    float4 x3 = ((const float4*)xr)[8 + kg * 2 + 1];
    if (arow >= N) {
        x0 = x1 = x2 = x3 = make_float4(0.f, 0.f, 0.f, 0.f);
    }

    short8v a_hi0, a_lo0, a_hi1, a_lo1;
    {
        const float t0[8] = {x0.x, x0.y, x0.z, x0.w, x1.x, x1.y, x1.z, x1.w};
        const float t1[8] = {x2.x, x2.y, x2.z, x2.w, x3.x, x3.y, x3.z, x3.w};
        #pragma unroll
        for (int e = 0; e < 8; ++e) {
            const ushort h = f2bf(t0[e]);
            a_hi0[e] = (short)h;
            a_lo0[e] = (short)f2bf(t0[e] - bf2f(h));
            const ushort g = f2bf(t1[e]);
            a_hi1[e] = (short)g;
            a_lo1[e] = (short)f2bf(t1[e] - bf2f(g));
        }
    }

    // C/D layout (HW-verified): col = lane&15, row = kg*4 + reg
    const int orow0 = block_row + wv * 16 + kg * 4;

    #pragma unroll
    for (int nt = 0; nt < NT; ++nt) {
        const int j = nt * 16 + col;            // output slot (0..143)
        const ushort* bhp = &w_hi[j * WSTRIDE + kg * 8];
        const ushort* blp = &w_lo[j * WSTRIDE + kg * 8];
        const short8v bh0 = *(const short8v*)bhp;          // c = kg*8+e
        const short8v bh1 = *(const short8v*)(bhp + 32);   // c = 32+kg*8+e
        const short8v bl0 = *(const short8v*)blp;
        const short8v bl1 = *(const short8v*)(blp + 32);

        f32x4 acc = {0.f, 0.f, 0.f, 0.f};
        // split-bf16 3-product: lo terms first, hi*hi last
        acc = __builtin_amdgcn_mfma_f32_16x16x32_bf16(a_lo0, bh0, acc, 0, 0, 0);
        acc = __builtin_amdgcn_mfma_f32_16x16x32_bf16(a_hi0, bl0, acc, 0, 0, 0);
        acc = __builtin_amdgcn_mfma_f32_16x16x32_bf16(a_lo1, bh1, acc, 0, 0, 0);
        acc = __builtin_amdgcn_mfma_f32_16x16x32_bf16(a_hi1, bl1, acc, 0, 0, 0);
        acc = __builtin_amdgcn_mfma_f32_16x16x32_bf16(a_hi0, bh0, acc, 0, 0, 0);
        acc = __builtin_amdgcn_mfma_f32_16x16x32_bf16(a_hi1, bh1, acc, 0, 0, 0);

        #pragma unroll
        for (int r = 0; r < 4; ++r) {
            const int row = orow0 + r;
            if (row < N) Zb[(size_t)row * PK + j] = f2bf(acc[r]);
        }
    }
}

// ---------------------------------------------------------------------------
// Kernel 2: edge messages + scatter-add (unsorted), r7's dense structure.
// Eager whole-row Zb loads on the UNPADDED layout: the 9-value row starts at
// halfword H = c*144 + p*9; load 5 dwords from the aligned-down base
// (dwordx4 + dword), then extract the 6-halfword spline window at
// S = (p&1) + 3*b1 with a branchless 2-stage funnel shift (alignbit+cndmask).
// Gather chain stays at 2 serial miss levels; no padding cost in the gemm.
// ---------------------------------------------------------------------------
#define EILP 8
template <bool USEBF>
__global__ __launch_bounds__(256) void edge_kernel(const int* __restrict__ ei,
                                                   const float* __restrict__ pos,
                                                   const float* __restrict__ pose,
                                                   const uint* __restrict__ pose_bf,
                                                   const ushort* __restrict__ Zb,
                                                   float* __restrict__ out,
                                                   int E) {
    const int p  = threadIdx.x & 15;
    const int eg = threadIdx.x >> 4;
    const int e0 = blockIdx.x * (16 * EILP) + eg;
    const uint oo = (uint)(p & 1);   // window start parity (lane-constant)

    int  r[EILP], c[EILP];
    bool valid[EILP];
    #pragma unroll
    for (int it = 0; it < EILP; ++it) {
        int e = e0 + it * 16;
        valid[it] = (e < E);
        int ec = valid[it] ? e : 0;
        r[it] = ei[ec];
        c[it] = ei[E + ec];
    }

    // --- eager independent gathers: pos, pose, and the full Zb row ---
    float d0[EILP], d1[EILP];
    #pragma unroll
    for (int it = 0; it < EILP; ++it) {
        const float2 pc = ((const float2*)pos)[c[it]];
        const float2 pr = ((const float2*)pos)[r[it]];
        d0[it] = (pc.x - pr.x) * INV2S;
        d1[it] = (pc.y - pr.y) * INV2S;
    }

    float a_[EILP], b_[EILP];
    #pragma unroll
    for (int it = 0; it < EILP; ++it) {
        if (USEBF) {
            const uint ab = pose_bf[(size_t)r[it] * P_DIM + p];
            a_[it] = bf2f((ushort)(ab & 0xffffu));
            b_[it] = bf2f((ushort)(ab >> 16));
        } else {
            const float2 ab = ((const float2*)pose)[(size_t)r[it] * P_DIM + p];
            a_[it] = ab.x;
            b_[it] = ab.y;
        }
    }

    uint4a qv[EILP];
    uint   q4[EILP];
    #pragma unroll
    for (int it = 0; it < EILP; ++it) {
        // dword base = floor((c*144 + p*9)/2) = c*72 + (p*9)>>1
        const uint* Zp = (const uint*)Zb + (size_t)c[it] * (PK / 2) + ((p * 9) >> 1);
        qv[it] = *(const uint4a*)Zp;   // dwordx4 (4B-aligned)
        q4[it] = Zp[4];
    }

    #pragma unroll
    for (int it = 0; it < EILP; ++it) {
        const float p0 = fmaf(a_[it], d0[it], fmaf(-b_[it], d1[it], 0.5f));
        const float p1 = fmaf(b_[it], d0[it], fmaf( a_[it], d1[it], 0.5f));

        const float v0 = fminf(fmaxf(p0, 0.0f), 1.0f) * 2.0f;
        const float v1 = fminf(fmaxf(p1, 0.0f), 1.0f) * 2.0f;
        // window base: b0 = (v0>=1), b1 = (v1>=1); fracs relative to base.
        // (at v==2: base 1, frac 1 -> weight on column 2; matches the
        //  reference's clamped i00==i01==2 case exactly)
        const bool b0 = (v0 >= 1.0f);
        const bool b1 = (v1 >= 1.0f);
        const float f0 = v0 - (b0 ? 1.0f : 0.0f);
        const float f1 = v1 - (b1 ? 1.0f : 0.0f);

        // --- 2-stage funnel shift: 6-halfword window at S = oo + 3*b1 ---
        const uint A0 = qv[it][0], A1 = qv[it][1], A2 = qv[it][2],
                   A3 = qv[it][3], A4 = q4[it];
        const bool s1 = (oo != 0) != b1;            // (S & 1) = oo ^ b1
        // stage 1: halfword-align (v_alignbit + cndmask)
        const uint h0 = s1 ? ((A0 >> 16) | (A1 << 16)) : A0;
        const uint h1 = s1 ? ((A1 >> 16) | (A2 << 16)) : A1;
        const uint h2 = s1 ? ((A2 >> 16) | (A3 << 16)) : A2;
        const uint h3 = s1 ? ((A3 >> 16) | (A4 << 16)) : A3;
        // stage 2: dword offset d = b1 ? (1 + oo) : 0
        const uint W0 = b1 ? (oo ? h2 : h1) : h0;
        const uint W1 = b1 ? (oo ? h3 : h2) : h1;
        const uint W2 = b1 ? (oo ? A4 : h3) : h2;   // oo&&b1 -> s1=0, A4 raw

        // taps: z00=w(b0), z10=w(b0+1), z01=w(b0+3), z11=w(b0+4)
        const uint s = b0 ? 16u : 0u;
        const float z00 = bf2f((ushort)(W0 >> s));
        const float z10 = bf2f((ushort)(b0 ? (W1 & 0xffffu) : (W0 >> 16)));
        const float z01 = bf2f((ushort)(b0 ? (W2 & 0xffffu) : (W1 >> 16)));
        const float z11 = bf2f((ushort)(W2 >> s));

        const float w00 = (1.0f - f0) * (1.0f - f1);
        const float w01 = (1.0f - f0) * f1;
        const float w10 = f0 * (1.0f - f1);
        const float w11 = f0 * f1;

        float m = w00 * z00;
        m = fmaf(w01, z01, m);
        m = fmaf(w10, z10, m);
        m = fmaf(w11, z11, m);

        if (valid[it]) atomicAdd(&out[(size_t)r[it] * P_DIM + p], m);
    }
}

// ---------------------------------------------------------------------------
extern "C" void kernel_launch(void* const* d_in, const int* in_sizes, int n_in,
                              void* d_out, int out_size, void* d_ws, size_t ws_size,
                              hipStream_t stream) {
    const float* x    = (const float*)d_in[0];
    const float* pos  = (const float*)d_in[1];
    const float* pose = (const float*)d_in[2];
    const float* W    = (const float*)d_in[3];
    const float* bias = (const float*)d_in[4];
    const int*   ei   = (const int*)d_in[5];

    const int N = in_sizes[0] / C_DIM;   // 50000
    const int E = in_sizes[5] / 2;       // 800000

    float* out = (float*)d_out;
    ushort* Zb = (ushort*)d_ws;          // N*144 bf16 = 14.4 MB (unpadded rows)

    // pose-bf16 table only if the workspace actually has room for it
    const size_t zb_bytes   = (size_t)N * PK * sizeof(ushort);
    const size_t pose_bytes = (size_t)N * P_DIM * sizeof(uint);
    uint* pose_bf = (ws_size >= zb_bytes + pose_bytes)
                        ? (uint*)((char*)d_ws + zb_bytes) : nullptr;

    z_gemm_kernel<<<(N + 63) / 64, 256, 0, stream>>>(x, W, bias, pose, out, Zb, pose_bf, N);

    const int eblocks = (E + 16 * EILP - 1) / (16 * EILP);
    if (pose_bf != nullptr)
        edge_kernel<true><<<eblocks, 256, 0, stream>>>(ei, pos, pose, pose_bf, Zb, out, E);
    else
        edge_kernel<false><<<eblocks, 256, 0, stream>>>(ei, pos, pose, pose_bf, Zb, out, E);
}

// Round 10
// 143.697 us; speedup vs baseline: 1.2110x; 1.0090x over previous
//
#include <hip/hip_runtime.h>

// Problem constants (fixed by the reference's setup_inputs)
#define C_DIM 64
#define P_DIM 16
#define K_DIM 9
#define ZROW 10              // padded Zb row (ushorts) per (n,p): 20 B
#define ZNODE (P_DIM * ZROW) // 160 ushorts = 320 B per node
#define NT 10                // n-tiles (permuted 160-slot output layout)
#define WELEM (160 * C_DIM)  // ushorts per W' table (10240)
#define INV2S 0.35355339059327373f  // 1/(2*sqrt(2))

typedef __attribute__((ext_vector_type(8))) short short8v;  // 8 bf16 (4 VGPRs)
typedef __attribute__((ext_vector_type(4))) float f32x4;    // MFMA accumulator
typedef uint uint4a __attribute__((ext_vector_type(4), aligned(4)));

__device__ __forceinline__ ushort f2bf(float f) {
    uint u = __builtin_bit_cast(uint, f);
    return (ushort)((u + 0x7FFFu + ((u >> 16) & 1u)) >> 16);   // RNE
}
__device__ __forceinline__ float bf2f(ushort h) {
    return __builtin_bit_cast(float, ((uint)h) << 16);
}

// ---------------------------------------------------------------------------
// Kernel 0 (prep, one-shot): (a) permuted W' -> global bf16 hi/lo tables
// (row j holds W[(j/10)*9 + j%10], zeros at j%10==9), (b) pose -> packed
// bf16 table, (c) bias-init of out. All grid-parallel, removes per-block
// convert work from the gemm entirely.
// ---------------------------------------------------------------------------
__global__ __launch_bounds__(256) void prep_kernel(const float* __restrict__ W,
                                                   const float* __restrict__ pose,
                                                   const float* __restrict__ bias,
                                                   float* __restrict__ out,
                                                   ushort* __restrict__ Whi,
                                                   ushort* __restrict__ Wlo,
                                                   uint* __restrict__ pose_bf,
                                                   int N) {
    const int g = blockIdx.x * 256 + threadIdx.x;
    const int gsz = gridDim.x * 256;

    // (a) W' tables: 5120 dwords per table
    if (g < WELEM / 2) {
        const int j  = g >> 5;           // W' row (0..159)
        const int k2 = g & 31;           // float2 index within row
        const int p  = j / 10;
        const int k  = j - p * 10;
        float2 w2 = make_float2(0.0f, 0.0f);
        if (k < 9) w2 = ((const float2*)W)[(p * 9 + k) * (C_DIM / 2) + k2];
        const ushort h0 = f2bf(w2.x);
        const ushort h1 = f2bf(w2.y);
        ((uint*)Whi)[g] = (uint)h0 | ((uint)h1 << 16);
        ((uint*)Wlo)[g] = (uint)f2bf(w2.x - bf2f(h0)) |
                          ((uint)f2bf(w2.y - bf2f(h1)) << 16);
    }

    // (b) pose -> packed bf16 (measured -3us on edge, r4 vs r5)
    if (pose_bf != nullptr) {
        for (int i = g; i < N * P_DIM; i += gsz) {
            const float2 ab = ((const float2*)pose)[i];
            pose_bf[i] = (uint)f2bf(ab.x) | ((uint)f2bf(ab.y) << 16);
        }
    }

    // (c) bias-init out: N*4 float4s
    {
        const float4 b4 = ((const float4*)bias)[g & 3];
        for (int i = g; i < N * 4; i += gsz) ((float4*)out)[i] = b4;
    }
}

// ---------------------------------------------------------------------------
// Kernel 1 (MFMA): Zb[n][s] (s = p*10+k, padded) = sum_c x[n,c]*W[p,k,c]
// via split-bf16 3-product MFMA. 64 rows/block, 4 waves.
// Staging = pure vector copy of the prepped tables (10x dwordx4 +
// ds_write_b128 per thread, zero convert VALU). LDS layout is XOR-swizzled
// (half ^= (row&7)<<3) on BOTH write and read -> even 8-lane/bank-quad
// spread on ds_read_b128. 40960B LDS -> exactly 4 blocks/CU.
// ---------------------------------------------------------------------------
__global__ __launch_bounds__(256) void z_gemm_kernel(const float* __restrict__ x,
                                                     const ushort* __restrict__ Whi,
                                                     const ushort* __restrict__ Wlo,
                                                     ushort* __restrict__ Zb,
                                                     int N) {
    __shared__ ushort w_hi[WELEM];   // 20480 B
    __shared__ ushort w_lo[WELEM];   // 20480 B

    const int tid = threadIdx.x;
    const int block_row = blockIdx.x * 64;

    // stage both tables: 160*16 uint4s each, swizzled LDS dest
    for (int i = tid; i < 160 * 16; i += 256) {
        const uint4 vh = ((const uint4*)Whi)[i];
        const uint4 vl = ((const uint4*)Wlo)[i];
        const int lin = i * 8;                    // half-offset (mult of 8)
        const int j   = lin >> 6;                 // row
        const int w   = lin & 63;
        const int swz = j * 64 + (w ^ ((j & 7) << 3));
        *(uint4*)&w_hi[swz] = vh;
        *(uint4*)&w_lo[swz] = vl;
    }
    __syncthreads();

    const int lane = tid & 63;
    const int wv   = tid >> 6;    // wave -> m-subtile (16 rows)
    const int col  = lane & 15;   // A row within tile / B,C/D column
    const int kg   = lane >> 4;   // k-group 0..3

    // A operand: lane supplies x[arow][kg*8 + e (+32*chunk)], split hi/lo.
    const int arow = block_row + wv * 16 + col;
    const float* xr = x + (size_t)(arow < N ? arow : 0) * C_DIM;
    float4 x0 = ((const float4*)xr)[kg * 2];
    float4 x1 = ((const float4*)xr)[kg * 2 + 1];
    float4 x2 = ((const float4*)xr)[8 + kg * 2];
    float4 x3 = ((const float4*)xr)[8 + kg * 2 + 1];
    if (arow >= N) {
        x0 = x1 = x2 = x3 = make_float4(0.f, 0.f, 0.f, 0.f);
    }

    short8v a_hi0, a_lo0, a_hi1, a_lo1;
    {
        const float t0[8] = {x0.x, x0.y, x0.z, x0.w, x1.x, x1.y, x1.z, x1.w};
        const float t1[8] = {x2.x, x2.y, x2.z, x2.w, x3.x, x3.y, x3.z, x3.w};
        #pragma unroll
        for (int e = 0; e < 8; ++e) {
            const ushort h = f2bf(t0[e]);
            a_hi0[e] = (short)h;
            a_lo0[e] = (short)f2bf(t0[e] - bf2f(h));
            const ushort g = f2bf(t1[e]);
            a_hi1[e] = (short)g;
            a_lo1[e] = (short)f2bf(t1[e] - bf2f(g));
        }
    }

    // C/D layout (HW-verified): col = lane&15, row = kg*4 + reg
    const int orow0 = block_row + wv * 16 + kg * 4;

    #pragma unroll
    for (int nt = 0; nt < NT; ++nt) {
        const int j  = nt * 16 + col;             // padded slot (0..159)
        const int sx = (j & 7) << 3;              // row swizzle
        const int b0off = j * 64 + ((kg * 8) ^ sx);
        const int b1off = j * 64 + ((32 + kg * 8) ^ sx);
        const short8v bh0 = *(const short8v*)&w_hi[b0off];
        const short8v bh1 = *(const short8v*)&w_hi[b1off];
        const short8v bl0 = *(const short8v*)&w_lo[b0off];
        const short8v bl1 = *(const short8v*)&w_lo[b1off];

        f32x4 acc = {0.f, 0.f, 0.f, 0.f};
        // split-bf16 3-product: lo terms first, hi*hi last
        acc = __builtin_amdgcn_mfma_f32_16x16x32_bf16(a_lo0, bh0, acc, 0, 0, 0);
        acc = __builtin_amdgcn_mfma_f32_16x16x32_bf16(a_hi0, bl0, acc, 0, 0, 0);
        acc = __builtin_amdgcn_mfma_f32_16x16x32_bf16(a_lo1, bh1, acc, 0, 0, 0);
        acc = __builtin_amdgcn_mfma_f32_16x16x32_bf16(a_hi1, bl1, acc, 0, 0, 0);
        acc = __builtin_amdgcn_mfma_f32_16x16x32_bf16(a_hi0, bh0, acc, 0, 0, 0);
        acc = __builtin_amdgcn_mfma_f32_16x16x32_bf16(a_hi1, bh1, acc, 0, 0, 0);

        // direct store: slot == j; 16 col-lanes -> 32B contiguous chunks
        #pragma unroll
        for (int r = 0; r < 4; ++r) {
            const int row = orow0 + r;
            if (row < N) Zb[(size_t)row * ZNODE + j] = f2bf(acc[r]);
        }
    }
}

// ---------------------------------------------------------------------------
// Kernel 2: edge messages + scatter-add (unsorted) — r7's measured-best
// structure (57.4us). Eager whole-row Zb loads (dwordx4 + dword) keep the
// gather chain at 2 serial miss levels; 4 spline taps selected in-register
// from the 6-halfword window at 3*b1.
// ---------------------------------------------------------------------------
#define EILP 8
template <bool USEBF>
__global__ __launch_bounds__(256) void edge_kernel(const int* __restrict__ ei,
                                                   const float* __restrict__ pos,
                                                   const float* __restrict__ pose,
                                                   const uint* __restrict__ pose_bf,
                                                   const ushort* __restrict__ Zb,
                                                   float* __restrict__ out,
                                                   int E) {
    const int p  = threadIdx.x & 15;
    const int eg = threadIdx.x >> 4;
    const int e0 = blockIdx.x * (16 * EILP) + eg;

    int  r[EILP], c[EILP];
    bool valid[EILP];
    #pragma unroll
    for (int it = 0; it < EILP; ++it) {
        int e = e0 + it * 16;
        valid[it] = (e < E);
        int ec = valid[it] ? e : 0;
        r[it] = ei[ec];
        c[it] = ei[E + ec];
    }

    // --- eager independent gathers: pos, pose, and the full Zb row ---
    float d0[EILP], d1[EILP];
    #pragma unroll
    for (int it = 0; it < EILP; ++it) {
        const float2 pc = ((const float2*)pos)[c[it]];
        const float2 pr = ((const float2*)pos)[r[it]];
        d0[it] = (pc.x - pr.x) * INV2S;
        d1[it] = (pc.y - pr.y) * INV2S;
    }

    float a_[EILP], b_[EILP];
    #pragma unroll
    for (int it = 0; it < EILP; ++it) {
        if (USEBF) {
            const uint ab = pose_bf[(size_t)r[it] * P_DIM + p];
            a_[it] = bf2f((ushort)(ab & 0xffffu));
            b_[it] = bf2f((ushort)(ab >> 16));
        } else {
            const float2 ab = ((const float2*)pose)[(size_t)r[it] * P_DIM + p];
            a_[it] = ab.x;
            b_[it] = ab.y;
        }
    }

    uint4a qv[EILP];
    uint   q4[EILP];
    #pragma unroll
    for (int it = 0; it < EILP; ++it) {
        const uint* Zp = (const uint*)(Zb + (size_t)c[it] * ZNODE) + p * (ZROW / 2);
        qv[it] = *(const uint4a*)Zp;   // dwordx4 (4B-aligned ok on gfx9+)
        q4[it] = Zp[4];
    }

    #pragma unroll
    for (int it = 0; it < EILP; ++it) {
        const float p0 = fmaf(a_[it], d0[it], fmaf(-b_[it], d1[it], 0.5f));
        const float p1 = fmaf(b_[it], d0[it], fmaf( a_[it], d1[it], 0.5f));

        const float v0 = fminf(fmaxf(p0, 0.0f), 1.0f) * 2.0f;
        const float v1 = fminf(fmaxf(p1, 0.0f), 1.0f) * 2.0f;
        // window base: b0 = (v0>=1), b1 = (v1>=1); fracs relative to base.
        // (at v==2: base 1, frac 1 -> weight on column 2; matches the
        //  reference's clamped i00==i01==2 case exactly)
        const bool b0 = (v0 >= 1.0f);
        const bool b1 = (v1 >= 1.0f);
        const float f0 = v0 - (b0 ? 1.0f : 0.0f);
        const float f1 = v1 - (b1 ? 1.0f : 0.0f);

        // 6-element window w0..w5 = e(3*b1) .. e(3*b1+5) as 3 dwords
        const uint A0 = qv[it][0], A1 = qv[it][1], A2 = qv[it][2],
                   A3 = qv[it][3], A4 = q4[it];
        const uint W0 = b1 ? ((A1 >> 16) | (A2 << 16)) : A0;
        const uint W1 = b1 ? ((A2 >> 16) | (A3 << 16)) : A1;
        const uint W2 = b1 ? ((A3 >> 16) | (A4 << 16)) : A2;
        // taps: z00=w(b0), z10=w(b0+1), z01=w(b0+3), z11=w(b0+4)
        const uint s = b0 ? 16u : 0u;
        const float z00 = bf2f((ushort)(W0 >> s));
        const float z10 = bf2f((ushort)(b0 ? (W1 & 0xffffu) : (W0 >> 16)));
        const float z01 = bf2f((ushort)(b0 ? (W2 & 0xffffu) : (W1 >> 16)));
        const float z11 = bf2f((ushort)(W2 >> s));

        const float w00 = (1.0f - f0) * (1.0f - f1);
        const float w01 = (1.0f - f0) * f1;
        const float w10 = f0 * (1.0f - f1);
        const float w11 = f0 * f1;

        float m = w00 * z00;
        m = fmaf(w01, z01, m);
        m = fmaf(w10, z10, m);
        m = fmaf(w11, z11, m);

        if (valid[it]) atomicAdd(&out[(size_t)r[it] * P_DIM + p], m);
    }
}

// ---------------------------------------------------------------------------
extern "C" void kernel_launch(void* const* d_in, const int* in_sizes, int n_in,
                              void* d_out, int out_size, void* d_ws, size_t ws_size,
                              hipStream_t stream) {
    const float* x    = (const float*)d_in[0];
    const float* pos  = (const float*)d_in[1];
    const float* pose = (const float*)d_in[2];
    const float* W    = (const float*)d_in[3];
    const float* bias = (const float*)d_in[4];
    const int*   ei   = (const int*)d_in[5];

    const int N = in_sizes[0] / C_DIM;   // 50000
    const int E = in_sizes[5] / 2;       // 800000

    float* out = (float*)d_out;

    // workspace layout: [Whi 20KB][Wlo 20KB][Zb 16MB][pose_bf 3.2MB gated]
    ushort* Whi = (ushort*)d_ws;
    ushort* Wlo = Whi + WELEM;
    ushort* Zb  = Wlo + WELEM;

    const size_t w_bytes    = (size_t)2 * WELEM * sizeof(ushort);
    const size_t zb_bytes   = (size_t)N * ZNODE * sizeof(ushort);
    const size_t pose_bytes = (size_t)N * P_DIM * sizeof(uint);
    uint* pose_bf = (ws_size >= w_bytes + zb_bytes + pose_bytes)
                        ? (uint*)((char*)Zb + zb_bytes) : nullptr;

    prep_kernel<<<3200, 256, 0, stream>>>(W, pose, bias, out, Whi, Wlo, pose_bf, N);
    z_gemm_kernel<<<(N + 63) / 64, 256, 0, stream>>>(x, Whi, Wlo, Zb, N);

    const int eblocks = (E + 16 * EILP - 1) / (16 * EILP);
    if (pose_bf != nullptr)
        edge_kernel<true><<<eblocks, 256, 0, stream>>>(ei, pos, pose, pose_bf, Zb, out, E);
    else
        edge_kernel<false><<<eblocks, 256, 0, stream>>>(ei, pos, pose, pose_bf, Zb, out, E);
}